// Round 8
// baseline (512.418 us; speedup 1.0000x reference)
//
#include <hip/hip_runtime.h>
#include <hip/hip_bf16.h>
#include <cstdint>

#define NWIN   1024
#define NTOK   98
#define BIAS_N 9604   // 98*98

typedef __attribute__((ext_vector_type(8))) short bf16x8;
typedef __attribute__((ext_vector_type(4))) float f32x4;

#define LDS_FENCE() asm volatile("s_waitcnt lgkmcnt(0)" ::: "memory")

__device__ __forceinline__ float b2f(unsigned short u) {
  union { uint32_t i; float f; } v; v.i = ((uint32_t)u) << 16; return v.f;
}
__device__ __forceinline__ float b2f_lo(uint32_t u) {
  union { uint32_t i; float f; } v; v.i = u << 16; return v.f;
}
__device__ __forceinline__ float b2f_hi(uint32_t u) {
  union { uint32_t i; float f; } v; v.i = u & 0xffff0000u; return v.f;
}
__device__ __forceinline__ unsigned short f2b(float f) {  // RNE
  union { float f; uint32_t i; } v; v.f = f;
  uint32_t r = v.i + 0x7fffu + ((v.i >> 16) & 1u);
  return (unsigned short)(r >> 16);
}
__device__ __forceinline__ float ldf(const void* p, size_t i, int f32) {
  return f32 ? ((const float*)p)[i] : b2f(((const unsigned short*)p)[i]);
}
__device__ __forceinline__ void stf(void* p, size_t i, int f32, float v) {
  if (f32) ((float*)p)[i] = v;
  else     ((unsigned short*)p)[i] = f2b(v);
}
__device__ __forceinline__ float2 ldf2(const void* p, size_t i, int f32) {  // i even
  if (f32) { const float* q = (const float*)p + i; return make_float2(q[0], q[1]); }
  uint32_t u = *(const uint32_t*)((const unsigned short*)p + i);
  return make_float2(b2f_lo(u), b2f_hi(u));
}

// ws offsets (bytes)
#define QG_OFF   0
#define KG_OFF   25690112
#define VG_OFF   51380224
#define BIAS_OFF 77070336    // f32, 153664 B
#define WQ_OFF   77224000    // bf16 [384][128]
#define WP_OFF   77322304    // bf16 [128][128]
#define W1_OFF   77355072    // bf16 [512][128]
#define W2_OFF   77486144    // bf16 [128][512]
#define PAR_OFF  77617216    // f32 x 1664
#define FLAG_OFF 77623872
// param layout (float idx)
#define P_LN1G 0
#define P_LN1B 128
#define P_LN2G 256
#define P_LN2B 384
#define P_QKVB 512
#define P_PROJB 896
#define P_B1  1024
#define P_B2  1536

// ---------------- K0: detect float-tensor storage format ----------------
__global__ __launch_bounds__(256) void detect_kernel(const uint32_t* __restrict__ xw,
                                                     int* __restrict__ flag) {
  __shared__ int cnt;
  if (threadIdx.x == 0) cnt = 0;
  __syncthreads();
  uint32_t w = xw[threadIdx.x];
  int e = (w >> 23) & 0xFF;
  if (e >= 112 && e <= 134) atomicAdd(&cnt, 1);
  __syncthreads();
  if (threadIdx.x == 0) *flag = (cnt >= 128) ? 1 : 0;
}

// ---------------- K1: weight transpose->bf16 + param->f32 ----------------
__global__ __launch_bounds__(256) void prep_kernel(
    const void* __restrict__ qkvw, const void* __restrict__ projw,
    const void* __restrict__ w1, const void* __restrict__ w2,
    const void* __restrict__ ln1g, const void* __restrict__ ln1b,
    const void* __restrict__ ln2g, const void* __restrict__ ln2b,
    const void* __restrict__ qkvb, const void* __restrict__ projb,
    const void* __restrict__ b1, const void* __restrict__ b2,
    const int* __restrict__ flag,
    unsigned short* __restrict__ wq_t, unsigned short* __restrict__ wp_t,
    unsigned short* __restrict__ w1_t, unsigned short* __restrict__ w2_t,
    float* __restrict__ par) {
  const int f32 = *flag;
  int idx = blockIdx.x * 256 + threadIdx.x;
  if (idx < 49152) {
    int n = idx >> 7, k = idx & 127;
    wq_t[idx] = f2b(ldf(qkvw, (size_t)k * 384 + n, f32));
  } else if ((idx -= 49152) < 16384) {
    int n = idx >> 7, k = idx & 127;
    wp_t[idx] = f2b(ldf(projw, (size_t)k * 128 + n, f32));
  } else if ((idx -= 16384) < 65536) {
    int n = idx >> 7, k = idx & 127;
    w1_t[idx] = f2b(ldf(w1, (size_t)k * 512 + n, f32));
  } else if ((idx -= 65536) < 65536) {
    int n = idx >> 9, k = idx & 511;
    w2_t[idx] = f2b(ldf(w2, (size_t)k * 128 + n, f32));
  } else if ((idx -= 65536) < 1664) {
    float v;
    if      (idx < 128)  v = ldf(ln1g, idx, f32);
    else if (idx < 256)  v = ldf(ln1b, idx - 128, f32);
    else if (idx < 384)  v = ldf(ln2g, idx - 256, f32);
    else if (idx < 512)  v = ldf(ln2b, idx - 384, f32);
    else if (idx < 896)  v = ldf(qkvb, idx - 512, f32);
    else if (idx < 1024) v = ldf(projb, idx - 896, f32);
    else if (idx < 1536) v = ldf(b1, idx - 1024, f32);
    else                 v = ldf(b2, idx - 1536, f32);
    par[idx] = v;
  }
}

// ---------------- K2: bias[h][i*98+j] = table[rel_idx[i,j]][h] ----------------
__global__ __launch_bounds__(256) void bias_kernel(const int* __restrict__ rel_idx,
                                                   const void* __restrict__ tbl,
                                                   const int* __restrict__ flag,
                                                   float* __restrict__ bias) {
  const int f32 = *flag;
  int i = blockIdx.x * 256 + threadIdx.x;
  if (i >= 4 * BIAS_N) return;
  int h = i / BIAS_N, ij = i % BIAS_N;
  bias[i] = ldf(tbl, (size_t)rel_idx[ij] * 4 + h, f32);
}

// ---------------- K3: per-window LN1+gather + QKV MFMA; coalesced q/k/v stores ----------------
__global__ __launch_bounds__(256) void qkv_win_kernel(
    const void* __restrict__ x, const int* __restrict__ flag,
    const unsigned short* __restrict__ wq_t, const float* __restrict__ par,
    unsigned short* __restrict__ qg, unsigned short* __restrict__ kg,
    unsigned short* __restrict__ vg) {
  __shared__ unsigned short lnx[112 * 136];   // 30464 B
  __shared__ unsigned short tile[112 * 68];   // 15232 B (out-stage)
  const int f32 = *flag;
  const int tid = threadIdx.x, wave = tid >> 6, lane = tid & 63;
  const int quad = lane >> 4, lcol = lane & 15;
  const int win = blockIdx.x;
  const int bb = win >> 8, r = win & 255;
  const int wd = r >> 6, r2 = r & 63, wh = r2 >> 3, ww = r2 & 7;

  for (int t = wave; t < NTOK; t += 4) {
    int td = t / 49, r3 = t % 49, th = r3 / 7, tw = r3 % 7;
    int sd = (wd * 2 + td + 1) & 7;
    int sh = (wh * 7 + th + 3) % 56;
    int sw = (ww * 7 + tw + 3) % 56;
    size_t src = ((((size_t)bb * 8 + sd) * 56 + sh) * 56 + sw) * 128;
    int c0 = lane * 2;
    float2 f = ldf2(x, src + c0, f32);
    float s = f.x + f.y, ss = f.x * f.x + f.y * f.y;
#pragma unroll
    for (int off = 32; off >= 1; off >>= 1) { s += __shfl_xor(s, off); ss += __shfl_xor(ss, off); }
    float mu = s * (1.0f / 128.0f);
    float var = ss * (1.0f / 128.0f) - mu * mu;
    float rs = rsqrtf(var + 1e-5f);
    float y0 = (f.x - mu) * rs * par[P_LN1G + c0] + par[P_LN1B + c0];
    float y1 = (f.y - mu) * rs * par[P_LN1G + c0 + 1] + par[P_LN1B + c0 + 1];
    *(uint32_t*)(lnx + t * 136 + c0) = (uint32_t)f2b(y0) | ((uint32_t)f2b(y1) << 16);
  }
  for (int i = tid; i < 14 * 68; i += 256) {
    int rr = i / 68, c = i % 68;
    *(uint32_t*)(lnx + (98 + rr) * 136 + c * 2) = 0u;
  }
  __syncthreads();

  for (int p = 0; p < 6; ++p) {
    const int n = p * 64 + wave * 16 + lcol;
    bf16x8 bfr[4];
#pragma unroll
    for (int ks = 0; ks < 4; ++ks)
      bfr[ks] = *(const bf16x8*)(wq_t + (size_t)n * 128 + ks * 32 + quad * 8);
    const float bc = par[P_QKVB + n];
    const float scale = (p < 2) ? 0.17677669529663687f : 1.0f;
    for (int mt = 0; mt < 7; ++mt) {
      f32x4 acc = (f32x4){0.f, 0.f, 0.f, 0.f};
#pragma unroll
      for (int ks = 0; ks < 4; ++ks) {
        bf16x8 a = *(const bf16x8*)(lnx + (mt * 16 + lcol) * 136 + ks * 32 + quad * 8);
        acc = __builtin_amdgcn_mfma_f32_16x16x32_bf16(a, bfr[ks], acc, 0, 0, 0);
      }
#pragma unroll
      for (int rr = 0; rr < 4; ++rr)
        tile[(mt * 16 + quad * 4 + rr) * 68 + wave * 16 + lcol] = f2b((acc[rr] + bc) * scale);
    }
    __syncthreads();
    const int region = p >> 1, head0 = (p & 1) * 2;
    unsigned short* dstg = (region == 0 ? qg : (region == 1 ? kg : vg)) +
                           ((size_t)win * 4) * NTOK * 32;
    for (int idx = tid; idx < NTOK * 32; idx += 256) {
      int t = idx >> 5, c = idx & 31;
      uint32_t w = *(const uint32_t*)(tile + t * 68 + 2 * c);
      int h = head0 + (c >> 4), d2 = (c & 15) * 2;
      *(uint32_t*)(dstg + ((size_t)h * NTOK + t) * 32 + d2) = w;
    }
    __syncthreads();
  }
}

// ---------------- K4: fused MFMA attention + proj + residual, 1 block/window ----------------
// wave = head; per-wave LDS tiles, per-wave lgkmcnt fences (no cross-wave barrier
// until the olds overlay). P/olds writes pair-packed via shfl_xor(1) -> <=2-way banks.
__global__ __launch_bounds__(256) void attn_fused_kernel(
    const unsigned short* __restrict__ qg, const unsigned short* __restrict__ kg,
    const unsigned short* __restrict__ vg, const float* __restrict__ bias,
    const unsigned short* __restrict__ wp_t, const float* __restrict__ par,
    const void* __restrict__ x, const int* __restrict__ flag,
    void* __restrict__ out) {
  __shared__ unsigned short smem[26112];   // 52224 B: vt[4][32*136] | pl[4][16*136]; olds overlays
  const int f32 = *flag;
  const int tid = threadIdx.x, wave = tid >> 6, lane = tid & 63;
  const int quad = lane >> 4, lcol = lane & 15;
  const int win = blockIdx.x, h = wave;
  const size_t hb = (((size_t)win * 4 + h) * NTOK) * 32;

  unsigned short* vth = smem + h * (32 * 136);
  unsigned short* plh = smem + 17408 + h * (16 * 136);

  // ---- stage V^T packed (2x2 transpose per lane): vt[d][j] = V[j][d] ----
  {
    const uint32_t* vsrc = (const uint32_t*)(vg + hb);
    for (int idx = lane; idx < 49 * 16; idx += 64) {
      int jq = idx >> 4, p = idx & 15;             // j-pair, d-pair
      uint32_t w0 = vsrc[(2 * jq) * 16 + p];       // V[2jq][2p..2p+1]
      uint32_t w1 = (2 * jq + 1 < NTOK) ? vsrc[(2 * jq + 1) * 16 + p] : 0u;
      *(uint32_t*)(vth + (2 * p) * 136 + 2 * jq)     = (w0 & 0xffffu) | (w1 << 16);
      *(uint32_t*)(vth + (2 * p + 1) * 136 + 2 * jq) = (w0 >> 16) | (w1 & 0xffff0000u);
    }
    for (int idx = lane; idx < 32 * 19; idx += 64) {   // zero vt cols 98..135
      int d = idx / 19, c = idx % 19;
      *(uint32_t*)(vth + d * 136 + 98 + 2 * c) = 0u;
    }
    for (int idx = lane; idx < 16 * 8; idx += 64) {    // zero pl cols 112..127
      int rr = idx >> 3, c = idx & 7;
      *(uint32_t*)(plh + rr * 136 + 112 + 2 * c) = 0u;
    }
  }
  LDS_FENCE();   // per-wave: staging visible to this wave

  // ---- Q/K fragments direct from global (rows clamped at 97) ----
  bf16x8 aq[7], bk[7];
#pragma unroll
  for (int t = 0; t < 7; ++t) {
    int row = min(t * 16 + lcol, NTOK - 1);
    aq[t] = *(const bf16x8*)(qg + hb + (size_t)row * 32 + quad * 8);
    bk[t] = *(const bf16x8*)(kg + hb + (size_t)row * 32 + quad * 8);
  }

  const float* bh = bias + h * BIAS_N;
  f32x4 o[7][2];
  for (int mt = 0; mt < 7; ++mt) {
    f32x4 s[7];
#pragma unroll
    for (int nt = 0; nt < 7; ++nt)
      s[nt] = __builtin_amdgcn_mfma_f32_16x16x32_bf16(aq[mt], bk[nt],
                                                      (f32x4){0.f, 0.f, 0.f, 0.f}, 0, 0, 0);
    const int ib = mt * 16 + quad * 4;
#pragma unroll
    for (int nt = 0; nt < 7; ++nt) {
      int j = nt * 16 + lcol;
      bool jv = j < NTOK;
#pragma unroll
      for (int r = 0; r < 4; ++r) {
        int ic = min(ib + r, NTOK - 1);
        s[nt][r] = jv ? (s[nt][r] + bh[ic * NTOK + j]) : -3.0e38f;
      }
    }
    float mx[4], sum[4], inv[4];
#pragma unroll
    for (int r = 0; r < 4; ++r) {
      float m = s[0][r];
#pragma unroll
      for (int nt = 1; nt < 7; ++nt) m = fmaxf(m, s[nt][r]);
      mx[r] = m;
    }
#pragma unroll
    for (int off = 1; off < 16; off <<= 1)
#pragma unroll
      for (int r = 0; r < 4; ++r) mx[r] = fmaxf(mx[r], __shfl_xor(mx[r], off));
#pragma unroll
    for (int r = 0; r < 4; ++r) sum[r] = 0.f;
#pragma unroll
    for (int nt = 0; nt < 7; ++nt)
#pragma unroll
      for (int r = 0; r < 4; ++r) {
        float e = __expf(s[nt][r] - mx[r]);
        s[nt][r] = e; sum[r] += e;
      }
#pragma unroll
    for (int off = 1; off < 16; off <<= 1)
#pragma unroll
      for (int r = 0; r < 4; ++r) sum[r] += __shfl_xor(sum[r], off);
#pragma unroll
    for (int r = 0; r < 4; ++r) inv[r] = 1.0f / sum[r];
    // packed P write (even lanes write u32; <=2-way banks)
#pragma unroll
    for (int nt = 0; nt < 7; ++nt)
#pragma unroll
      for (int r = 0; r < 4; ++r) {
        unsigned short pb = f2b(s[nt][r] * inv[r]);
        int other = __shfl_xor((int)pb, 1);
        if (!(lcol & 1))
          *(uint32_t*)(plh + (quad * 4 + r) * 136 + nt * 16 + lcol) =
              (uint32_t)pb | ((uint32_t)other << 16);
      }
    LDS_FENCE();   // per-wave: P visible before PV reads
#pragma unroll
    for (int n2 = 0; n2 < 2; ++n2) {
      f32x4 acc = (f32x4){0.f, 0.f, 0.f, 0.f};
#pragma unroll
      for (int kp = 0; kp < 4; ++kp) {
        bf16x8 a = *(const bf16x8*)(plh + lcol * 136 + kp * 32 + quad * 8);
        bf16x8 b = *(const bf16x8*)(vth + (n2 * 16 + lcol) * 136 + kp * 32 + quad * 8);
        acc = __builtin_amdgcn_mfma_f32_16x16x32_bf16(a, b, acc, 0, 0, 0);
      }
      o[mt][n2] = acc;
    }
  }
  __syncthreads();   // all waves done with vt/pl before olds overlays

  // ---- attn-out -> LDS [112][136] (packed writes) ----
  unsigned short* olds = smem;
#pragma unroll
  for (int mt = 0; mt < 7; ++mt)
#pragma unroll
    for (int n2 = 0; n2 < 2; ++n2)
#pragma unroll
      for (int r = 0; r < 4; ++r) {
        unsigned short ov = f2b(o[mt][n2][r]);
        int other = __shfl_xor((int)ov, 1);
        if (!(lcol & 1))
          *(uint32_t*)(olds + (mt * 16 + quad * 4 + r) * 136 + h * 32 + n2 * 16 + lcol) =
              (uint32_t)ov | ((uint32_t)other << 16);
      }
  __syncthreads();

  // ---- proj + bias + residual scatter (reverse roll) ----
  const int bb = win >> 8, rW = win & 255;
  const int wd = rW >> 6, r2 = rW & 63, wh = r2 >> 3, ww = r2 & 7;
  for (int t2 = 0; t2 < 2; ++t2) {
    const int n = (h * 2 + t2) * 16 + lcol;
    bf16x8 bw[4];
#pragma unroll
    for (int kp = 0; kp < 4; ++kp)
      bw[kp] = *(const bf16x8*)(wp_t + (size_t)n * 128 + kp * 32 + quad * 8);
    const float bc = par[P_PROJB + n];
    for (int mt = 0; mt < 7; ++mt) {
      f32x4 acc = (f32x4){0.f, 0.f, 0.f, 0.f};
#pragma unroll
      for (int kp = 0; kp < 4; ++kp) {
        bf16x8 a = *(const bf16x8*)(olds + (mt * 16 + lcol) * 136 + kp * 32 + quad * 8);
        acc = __builtin_amdgcn_mfma_f32_16x16x32_bf16(a, bw[kp], acc, 0, 0, 0);
      }
#pragma unroll
      for (int r = 0; r < 4; ++r) {
        int m = mt * 16 + quad * 4 + r;
        if (m < NTOK) {
          int td = m / 49, r3 = m % 49, th = r3 / 7, tw = r3 % 7;
          int sd = (wd * 2 + td + 1) & 7;
          int sh = (wh * 7 + th + 3) % 56;
          int sw = (ww * 7 + tw + 3) % 56;
          size_t oidx = ((((size_t)bb * 8 + sd) * 56 + sh) * 56 + sw) * 128 + n;
          stf(out, oidx, f32, acc[r] + bc + ldf(x, oidx, f32));
        }
      }
    }
  }
}

// ---------------- K5: LN2 + MLP1(gelu) + MLP2 + residual ----------------
__global__ __launch_bounds__(256) void mlp_kernel(
    const unsigned short* __restrict__ w1_t, const unsigned short* __restrict__ w2_t,
    const float* __restrict__ par, const int* __restrict__ flag,
    void* __restrict__ out) {
  __shared__ unsigned short lnt[32 * 136];
  __shared__ unsigned short hbuf[32 * 520];
  const int f32 = *flag;
  const int tid = threadIdx.x, wave = tid >> 6, lane = tid & 63;
  const int quad = lane >> 4, lcol = lane & 15;
  const int m0 = blockIdx.x * 32;

  for (int t = wave; t < 32; t += 4) {
    int c0 = lane * 2;
    float2 f = ldf2(out, (size_t)(m0 + t) * 128 + c0, f32);
    float s = f.x + f.y, ss = f.x * f.x + f.y * f.y;
#pragma unroll
    for (int off = 32; off >= 1; off >>= 1) { s += __shfl_xor(s, off); ss += __shfl_xor(ss, off); }
    float mu = s * (1.0f / 128.0f);
    float var = ss * (1.0f / 128.0f) - mu * mu;
    float rs = rsqrtf(var + 1e-5f);
    float y0 = (f.x - mu) * rs * par[P_LN2G + c0] + par[P_LN2B + c0];
    float y1 = (f.y - mu) * rs * par[P_LN2G + c0 + 1] + par[P_LN2B + c0 + 1];
    *(uint32_t*)(lnt + t * 136 + c0) = (uint32_t)f2b(y0) | ((uint32_t)f2b(y1) << 16);
  }
  __syncthreads();

  for (int p = 0; p < 8; ++p) {
    const int n = p * 64 + wave * 16 + lcol;
    bf16x8 bfr[4];
#pragma unroll
    for (int ks = 0; ks < 4; ++ks)
      bfr[ks] = *(const bf16x8*)(w1_t + (size_t)n * 128 + ks * 32 + quad * 8);
    const float bc = par[P_B1 + n];
#pragma unroll
    for (int mt = 0; mt < 2; ++mt) {
      f32x4 acc = (f32x4){0.f, 0.f, 0.f, 0.f};
#pragma unroll
      for (int ks = 0; ks < 4; ++ks) {
        bf16x8 a = *(const bf16x8*)(lnt + (mt * 16 + lcol) * 136 + ks * 32 + quad * 8);
        acc = __builtin_amdgcn_mfma_f32_16x16x32_bf16(a, bfr[ks], acc, 0, 0, 0);
      }
#pragma unroll
      for (int rr = 0; rr < 4; ++rr) {
        int m = mt * 16 + quad * 4 + rr;
        float v = acc[rr] + bc;
        v = 0.5f * v * (1.0f + erff(v * 0.70710678118654752f));
        unsigned short hv = f2b(v);
        int other = __shfl_xor((int)hv, 1);
        if (!(lcol & 1))
          *(uint32_t*)(hbuf + m * 520 + n) = (uint32_t)hv | ((uint32_t)other << 16);
      }
    }
  }
  __syncthreads();

  f32x4 acc2[2][2];
#pragma unroll
  for (int a = 0; a < 2; ++a)
#pragma unroll
    for (int b = 0; b < 2; ++b) acc2[a][b] = (f32x4){0.f, 0.f, 0.f, 0.f};
#pragma unroll
  for (int np = 0; np < 2; ++np) {
    const int n = np * 64 + wave * 16 + lcol;
    for (int kp = 0; kp < 4; ++kp) {
      bf16x8 bfr[4];
#pragma unroll
      for (int ks = 0; ks < 4; ++ks)
        bfr[ks] = *(const bf16x8*)(w2_t + (size_t)n * 512 + kp * 128 + ks * 32 + quad * 8);
#pragma unroll
      for (int mt = 0; mt < 2; ++mt) {
#pragma unroll
        for (int ks = 0; ks < 4; ++ks) {
          bf16x8 a = *(const bf16x8*)(hbuf + (mt * 16 + lcol) * 520 + kp * 128 +
                                      ks * 32 + quad * 8);
          acc2[np][mt] = __builtin_amdgcn_mfma_f32_16x16x32_bf16(a, bfr[ks], acc2[np][mt], 0, 0, 0);
        }
      }
    }
  }
#pragma unroll
  for (int np = 0; np < 2; ++np) {
    const int n = np * 64 + wave * 16 + lcol;
    const float bc = par[P_B2 + n];
#pragma unroll
    for (int mt = 0; mt < 2; ++mt) {
#pragma unroll
      for (int rr = 0; rr < 4; ++rr) {
        size_t oi = (size_t)(m0 + mt * 16 + quad * 4 + rr) * 128 + n;
        stf(out, oi, f32, acc2[np][mt][rr] + bc + ldf(out, oi, f32));
      }
    }
  }
}

// ---------------- host launch ----------------
extern "C" void kernel_launch(void* const* d_in, const int* in_sizes, int n_in,
                              void* d_out, int out_size, void* d_ws, size_t ws_size,
                              hipStream_t stream) {
  const void* x      = d_in[0];
  const int*  rel    = (const int*)d_in[1];
  const void* rpb    = d_in[2];
  const void* qkv_w  = d_in[3];
  const void* qkv_b  = d_in[4];
  const void* proj_w = d_in[5];
  const void* proj_b = d_in[6];
  const void* ln1_g  = d_in[7];
  const void* ln1_b  = d_in[8];
  const void* ln2_g  = d_in[9];
  const void* ln2_b  = d_in[10];
  const void* w1     = d_in[11];
  const void* b1     = d_in[12];
  const void* w2     = d_in[13];
  const void* b2     = d_in[14];

  char* ws = (char*)d_ws;
  unsigned short* qg   = (unsigned short*)(ws + QG_OFF);
  unsigned short* kg   = (unsigned short*)(ws + KG_OFF);
  unsigned short* vg   = (unsigned short*)(ws + VG_OFF);
  float*          bias = (float*)(ws + BIAS_OFF);
  unsigned short* wq_t = (unsigned short*)(ws + WQ_OFF);
  unsigned short* wp_t = (unsigned short*)(ws + WP_OFF);
  unsigned short* w1_t = (unsigned short*)(ws + W1_OFF);
  unsigned short* w2_t = (unsigned short*)(ws + W2_OFF);
  float*          par  = (float*)(ws + PAR_OFF);
  int*            flag = (int*)(ws + FLAG_OFF);

  detect_kernel<<<1, 256, 0, stream>>>((const uint32_t*)x, flag);
  prep_kernel<<<775, 256, 0, stream>>>(qkv_w, proj_w, w1, w2, ln1_g, ln1_b, ln2_g,
                                       ln2_b, qkv_b, proj_b, b1, b2, flag,
                                       wq_t, wp_t, w1_t, w2_t, par);
  bias_kernel<<<(4 * BIAS_N + 255) / 256, 256, 0, stream>>>(rel, rpb, flag, bias);
  qkv_win_kernel<<<NWIN, 256, 0, stream>>>(x, flag, wq_t, par, qg, kg, vg);
  attn_fused_kernel<<<NWIN, 256, 0, stream>>>(qg, kg, vg, bias, wp_t, par, x, flag, d_out);
  mlp_kernel<<<100352 / 32, 256, 0, stream>>>(w1_t, w2_t, par, flag, d_out);
}